// Round 1
// 1663.150 us; speedup vs baseline: 2.7690x; 2.7690x over previous
//
#include <hip/hip_runtime.h>
#include <stdint.h>

// 3-layer LSTM (H=256, B=256, T=512), persistent pipelined kernel.
// Partition: per layer, GB=8 batch-groups (32 rows) x GH=8 hidden-groups (32 units)
//   -> 192 workgroups of 512 threads (8 waves).
// Waves: (tau, mh) = (gate type i/f/g/o, batch half). Each wave holds its
// weight slice [32 gate rows x 512 K] as bf16 MFMA B-fragments in 128 regs.
// h exchanged through a global bf16 ring (depth 4), relaxed agent-scope
// (sc0 sc1, LLC-coherent) stores.
//
// R2 change vs R1 (4605 us): the per-step h-ring READS were 8 waves x 32 x 8B
// agent-scope atomic loads per WG (16K LLC-bypass requests/WG/step, 4x
// redundant across the tau-waves, 2.6M requests/step chip-wide ~ 120 req/cyc
// = fabric service ceiling; MfmaUtil 2.9% / VALU 7% / HBM 1% -> request-rate
// bound). Now each WG stages the two 16KB h-tiles into LDS once via
// inline-asm global_load_dwordx4 sc0 sc1 (4 x 16B per thread = 2048
// requests/WG/step, 8x fewer), fragment-major LDS layout so staging writes
// are tid-linear and ds_read_b128 fragment reads are conflict-free.

#define Hd 256
#define Bd 256
#define Td 512
#define RING 4
#define GH 8
#define GB 8
#define CPAD 32   // 32 uints = 128 B between flag counters

typedef __attribute__((ext_vector_type(8))) short short8;
typedef __attribute__((ext_vector_type(4))) float floatx4;
typedef __attribute__((ext_vector_type(4))) unsigned int uintx4;

__device__ __forceinline__ unsigned short f2bf(float f) {
  union { float f; unsigned int u; } v; v.f = f;
  return (unsigned short)((v.u + 0x7fffu + ((v.u >> 16) & 1u)) >> 16);
}
__device__ __forceinline__ float sigm(float x) { return 1.0f / (1.0f + __expf(-x)); }
__device__ __forceinline__ float tanhfast(float x) { return 2.0f / (1.0f + __expf(-2.0f * x)) - 1.0f; }

__device__ __forceinline__ void spin_relaxed(unsigned int* p, unsigned int v) {
  while (__hip_atomic_load(p, __ATOMIC_RELAXED, __HIP_MEMORY_SCOPE_AGENT) < v) { }
}

__global__ __launch_bounds__(512, 2) void lstm3_kernel(
    const float* __restrict__ xin,
    const float* __restrict__ Wi1, const float* __restrict__ Wh1,
    const float* __restrict__ bi1, const float* __restrict__ bh1,
    const float* __restrict__ Wi2, const float* __restrict__ Wh2,
    const float* __restrict__ bi2, const float* __restrict__ bh2,
    const float* __restrict__ Wi3, const float* __restrict__ Wh3,
    const float* __restrict__ bi3, const float* __restrict__ bh3,
    const float* __restrict__ Wlin, const float* __restrict__ blin,
    float* __restrict__ out,                // [B][T], pre-zeroed
    unsigned int* __restrict__ cnt,         // [3*GB*CPAD], pre-zeroed
    unsigned short* __restrict__ ring)      // [3][RING][B][H] bf16
{
  __shared__ float gl[4][32][33];       // [gate][local row][local unit(+pad)]
  __shared__ uintx4 hbuf[2][1024];      // [0]=up h(t), [1]=own h(t-1); fragment-major
                                        // chunk cidx = kc*128 + row*4 + quad (16B each)

  const int bid = blockIdx.x;
  const int j   = bid / 24;         // hidden group 0..7
  const int rem = bid - j * 24;
  const int l   = rem >> 3;         // layer 0..2
  const int g   = rem & 7;          // batch group 0..7 (bid%8 -> same XCD, perf only)

  const int tid  = threadIdx.x;
  const int lane = tid & 63;
  const int wave = tid >> 6;
  const int tau  = wave & 3;        // gate: 0=i 1=f 2=g 3=o
  const int mh   = wave >> 2;       // batch half
  const int quad = lane >> 4;
  const int l15  = lane & 15;

  const int ubase = j * 32;
  const int rbase = g * 32;

  const float* Wpi = (l == 1) ? Wi2 : Wi3;
  const float* Wph = (l == 0) ? Wh1 : ((l == 1) ? Wh2 : Wh3);
  const float* bi  = (l == 0) ? bi1 : ((l == 1) ? bi2 : bi3);
  const float* bh  = (l == 0) ? bh1 : ((l == 1) ? bh2 : bh3);

  // ---- one-time: weight slice -> bf16 B-fragments in registers ----
  short8 breg[2][16];
  {
    const int koff = quad * 8;
    #pragma unroll
    for (int nt = 0; nt < 2; ++nt) {
      const int grow = tau * Hd + ubase + nt * 16 + l15;
      #pragma unroll
      for (int kc = 0; kc < 16; ++kc) {
        short8 v = {0, 0, 0, 0, 0, 0, 0, 0};
        const float* src = nullptr;
        if (kc < 8) { if (l != 0) src = Wpi + (size_t)grow * Hd + kc * 32 + koff; }
        else        { src = Wph + (size_t)grow * Hd + (kc - 8) * 32 + koff; }
        if (src) {
          #pragma unroll
          for (int e = 0; e < 8; ++e) v[e] = (short)f2bf(src[e]);
        }
        breg[nt][kc] = v;
      }
    }
  }

  // ---- combine-phase per-thread constants ----
  const int clrow = tid >> 4;
  const int cu0   = (tid & 15) * 2;
  float bsum[4][2], wiv[4][2], wlv[2];
  #pragma unroll
  for (int tt = 0; tt < 4; ++tt) {
    #pragma unroll
    for (int du = 0; du < 2; ++du) {
      const int gg = tt * Hd + ubase + cu0 + du;
      bsum[tt][du] = bi[gg] + bh[gg];
      wiv[tt][du]  = (l == 0) ? Wi1[gg] : 0.0f;
    }
  }
  wlv[0] = (l == 2) ? Wlin[ubase + cu0]     : 0.0f;
  wlv[1] = (l == 2) ? Wlin[ubase + cu0 + 1] : 0.0f;
  const float bl0 = (l == 2 && j == 0) ? blin[0] : 0.0f;

  float cst0 = 0.0f, cst1 = 0.0f;

  unsigned int* myC = cnt + (l * GB + g) * CPAD;
  unsigned int* upC = cnt + ((l - 1) * GB + g) * CPAD;   // deref only if l>0
  unsigned int* dnC = cnt + ((l + 1) * GB + g) * CPAD;   // deref only if l<2
  unsigned short* ownR = ring + (size_t)l * RING * Bd * Hd;
  const unsigned short* upRb = ring + (size_t)(l - 1) * RING * Bd * Hd;

  const float* xrow = xin + (size_t)(rbase + clrow) * Td;

  // ---- staging geometry: thread -> two 16B chunks, LDS-linear ----
  // cidx = kc*128 + row*4 + q ; lds byte = cidx*16 ; global byte in 16KB tile:
  //   o = row*512 + kc*64 + q*16
  const int c0 = tid;
  const int c1 = tid + 512;
  const int o0 = ((c0 >> 2) & 31) * 512 + (c0 >> 7) * 64 + (c0 & 3) * 16;
  const int o1 = ((c1 >> 2) & 31) * 512 + (c1 >> 7) * 64 + (c1 & 3) * 16;
  const int fragbase = (mh * 16 + l15) * 4 + quad;

  // zero own-h tile so t==0 reads h(-1)=0 (ordered by barriers of step 0)
  {
    uintx4 z = {0u, 0u, 0u, 0u};
    hbuf[1][c0] = z;
    hbuf[1][c1] = z;
  }

  for (int t = 0; t < Td; ++t) {
    // ---- waits, lane-parallel: lanes 0/1/2 poll the three conditions ----
    {
      bool active = false; unsigned int* p = nullptr; unsigned need = 0;
      if (tid == 0)      { active = (t > 0);                p = myC; need = GH * t; }
      else if (tid == 1) { active = (l > 0);                p = upC; need = GH * (t + 1); }
      else if (tid == 2) { active = (l < 2) && (t >= RING); p = dnC; need = GH * (t - RING + 1); }
      if (active) spin_relaxed(p, need);
    }
    __syncthreads();

    // ---- stage h tiles -> LDS: 16B coherent loads, issue-all then one wait ----
    uintx4 u0, u1, v0, v1;
    if (l != 0) {
      const char* upReg = (const char*)(upRb + (size_t)(t & (RING - 1)) * Bd * Hd
                                        + (size_t)rbase * Hd);
      asm volatile("global_load_dwordx4 %0, %1, off sc0 sc1"
                   : "=&v"(u0) : "v"(upReg + o0));
      asm volatile("global_load_dwordx4 %0, %1, off sc0 sc1"
                   : "=&v"(u1) : "v"(upReg + o1));
    }
    if (t != 0) {
      const char* ownReg = (const char*)(ownR + (size_t)((t + RING - 1) & (RING - 1)) * Bd * Hd
                                         + (size_t)rbase * Hd);
      asm volatile("global_load_dwordx4 %0, %1, off sc0 sc1"
                   : "=&v"(v0) : "v"(ownReg + o0));
      asm volatile("global_load_dwordx4 %0, %1, off sc0 sc1"
                   : "=&v"(v1) : "v"(ownReg + o1));
    }
    asm volatile("s_waitcnt vmcnt(0)" ::: "memory");
    if (l != 0) { hbuf[0][c0] = u0; hbuf[0][c1] = u1; }
    if (t != 0) { hbuf[1][c0] = v0; hbuf[1][c1] = v1; }
    __syncthreads();

    // ---- A-fragments from LDS (conflict-free: 64 consecutive 16B chunks) ----
    short8 av[16];
    if (l != 0) {
      #pragma unroll
      for (int kc = 0; kc < 8; ++kc)
        av[kc] = *reinterpret_cast<const short8*>(&hbuf[0][kc * 128 + fragbase]);
    }
    #pragma unroll
    for (int kc = 0; kc < 8; ++kc)
      av[8 + kc] = *reinterpret_cast<const short8*>(&hbuf[1][kc * 128 + fragbase]);

    // ---- MFMA: gates[32 rows][32 units] for gate-type tau ----
    floatx4 acc0 = {0.f, 0.f, 0.f, 0.f};
    floatx4 acc1 = {0.f, 0.f, 0.f, 0.f};
    if (l != 0) {
      #pragma unroll
      for (int kc = 0; kc < 8; ++kc) {
        acc0 = __builtin_amdgcn_mfma_f32_16x16x32_bf16(av[kc], breg[0][kc], acc0, 0, 0, 0);
        acc1 = __builtin_amdgcn_mfma_f32_16x16x32_bf16(av[kc], breg[1][kc], acc1, 0, 0, 0);
      }
    }
    #pragma unroll
    for (int kc = 8; kc < 16; ++kc) {
      acc0 = __builtin_amdgcn_mfma_f32_16x16x32_bf16(av[kc], breg[0][kc], acc0, 0, 0, 0);
      acc1 = __builtin_amdgcn_mfma_f32_16x16x32_bf16(av[kc], breg[1][kc], acc1, 0, 0, 0);
    }

    // C layout: col(unit) = lane&15, row = quad*4 + reg
    {
      const int lr = mh * 16 + quad * 4;
      #pragma unroll
      for (int r2 = 0; r2 < 4; ++r2) {
        gl[tau][lr + r2][l15]      = acc0[r2];
        gl[tau][lr + r2][16 + l15] = acc1[r2];
      }
    }
    __syncthreads();

    // ---- combine: 1 row x 2 units per thread, fp32 LSTM cell math ----
    float h0, h1;
    {
      const float xv = (l == 0) ? xrow[t] : 0.0f;
      float pi = gl[0][clrow][cu0] + bsum[0][0] + xv * wiv[0][0];
      float pf = gl[1][clrow][cu0] + bsum[1][0] + xv * wiv[1][0];
      float pg = gl[2][clrow][cu0] + bsum[2][0] + xv * wiv[2][0];
      float po = gl[3][clrow][cu0] + bsum[3][0] + xv * wiv[3][0];
      float ii = sigm(pi), ff = sigm(pf), gv = tanhfast(pg), oo = sigm(po);
      cst0 = ff * cst0 + ii * gv;
      h0 = oo * tanhfast(cst0);
      pi = gl[0][clrow][cu0 + 1] + bsum[0][1] + xv * wiv[0][1];
      pf = gl[1][clrow][cu0 + 1] + bsum[1][1] + xv * wiv[1][1];
      pg = gl[2][clrow][cu0 + 1] + bsum[2][1] + xv * wiv[2][1];
      po = gl[3][clrow][cu0 + 1] + bsum[3][1] + xv * wiv[3][1];
      ii = sigm(pi); ff = sigm(pf); gv = tanhfast(pg); oo = sigm(po);
      cst1 = ff * cst1 + ii * gv;
      h1 = oo * tanhfast(cst1);
    }

    // store h pair (LLC write-through, relaxed)
    {
      unsigned short* dst = ownR + (size_t)(t & (RING - 1)) * Bd * Hd
                          + (size_t)(rbase + clrow) * Hd + ubase + cu0;
      const unsigned int packed = (unsigned int)f2bf(h0) | ((unsigned int)f2bf(h1) << 16);
      __hip_atomic_store((unsigned int*)dst, packed, __ATOMIC_RELAXED,
                         __HIP_MEMORY_SCOPE_AGENT);
    }

    // ---- output head folded into layer 3 ----
    if (l == 2) {
      float pr = wlv[0] * h0 + wlv[1] * h1;
      pr += __shfl_xor(pr, 8);
      pr += __shfl_xor(pr, 4);
      pr += __shfl_xor(pr, 2);
      pr += __shfl_xor(pr, 1);
      if ((tid & 15) == 0) {
        atomicAdd(&out[(size_t)(rbase + clrow) * Td + t], pr + bl0);
      }
    }

    __syncthreads();   // barrier drains vmcnt: all h-stores at LLC before flag
    if (tid == 0) {
      __hip_atomic_fetch_add(myC, 1u, __ATOMIC_RELAXED, __HIP_MEMORY_SCOPE_AGENT);
    }
  }
}

extern "C" void kernel_launch(void* const* d_in, const int* in_sizes, int n_in,
                              void* d_out, int out_size, void* d_ws, size_t ws_size,
                              hipStream_t stream) {
  const float* xin  = (const float*)d_in[0];
  const float* Wi1  = (const float*)d_in[1];
  const float* Wh1  = (const float*)d_in[2];
  const float* bi1  = (const float*)d_in[3];
  const float* bh1  = (const float*)d_in[4];
  const float* Wi2  = (const float*)d_in[5];
  const float* Wh2  = (const float*)d_in[6];
  const float* bi2  = (const float*)d_in[7];
  const float* bh2  = (const float*)d_in[8];
  const float* Wi3  = (const float*)d_in[9];
  const float* Wh3  = (const float*)d_in[10];
  const float* bi3  = (const float*)d_in[11];
  const float* bh3  = (const float*)d_in[12];
  const float* Wlin = (const float*)d_in[13];
  const float* blin = (const float*)d_in[14];
  float* out = (float*)d_out;

  unsigned int*   cnt  = (unsigned int*)d_ws;
  unsigned short* ring = (unsigned short*)((char*)d_ws + 4096);
  // ws usage: 4096 B padded counters + 3*RING*B*H*2 B rings (~1.5 MB)

  hipMemsetAsync(d_ws, 0, 4096, stream);
  hipMemsetAsync(d_out, 0, (size_t)out_size * sizeof(float), stream);

  lstm3_kernel<<<dim3(3 * GB * GH), dim3(512), 0, stream>>>(
      xin, Wi1, Wh1, bi1, bh1, Wi2, Wh2, bi2, bh2,
      Wi3, Wh3, bi3, bh3, Wlin, blin, out, cnt, ring);
}